// Round 1
// 267.261 us; speedup vs baseline: 1.0374x; 1.0374x over previous
//
#include <hip/hip_runtime.h>
#include <hip/hip_bf16.h>
#include <float.h>
#include <math.h>

#define N 4096
#define DIN 64

typedef signed char i8_t;
typedef signed char i8x4 __attribute__((ext_vector_type(4)));
typedef int i32x4 __attribute__((ext_vector_type(4)));
typedef float f32x4 __attribute__((ext_vector_type(4)));

// ---------- async global->LDS, 16B per lane ----------
__device__ __forceinline__ void gload16(const void* g, void* l) {
    __builtin_amdgcn_global_load_lds((const __attribute__((address_space(1))) void*)g,
                                     (__attribute__((address_space(3))) void*)l,
                                     16, 0, 0);
}

__device__ __forceinline__ float block_reduce_sum(float s) {
    __shared__ float red[4];
    #pragma unroll
    for (int off = 32; off; off >>= 1) s += __shfl_down(s, off);
    if ((threadIdx.x & 63) == 0) red[threadIdx.x >> 6] = s;
    __syncthreads();
    return red[0] + red[1] + red[2] + red[3];
}

// ---------- top-4 insertion with tie -> lower index ----------
__device__ __forceinline__ bool better(float v1, int j1, float v2, int j2) {
    return v1 > v2 || (v1 == v2 && j1 < j2);
}
__device__ __forceinline__ void ins4(float v, int j, float bv[4], int bj[4]) {
    if (!better(v, j, bv[3], bj[3])) return;
    bv[3] = v; bj[3] = j;
    if (better(bv[3], bj[3], bv[2], bj[2])) {
        float tv = bv[2]; int tj = bj[2]; bv[2] = bv[3]; bj[2] = bj[3]; bv[3] = tv; bj[3] = tj;
    }
    if (better(bv[2], bj[2], bv[1], bj[1])) {
        float tv = bv[1]; int tj = bj[1]; bv[1] = bv[2]; bj[1] = bj[2]; bv[2] = tv; bj[2] = tj;
    }
    if (better(bv[1], bj[1], bv[0], bj[0])) {
        float tv = bv[0]; int tj = bj[0]; bv[0] = bv[1]; bj[0] = bj[1]; bv[1] = tv; bj[1] = tj;
    }
}

// ---------- K1: rowsums of A -> dinv = 1/sqrt(d); also zero rowsumP ----------
__global__ __launch_bounds__(256) void k_rowsum_dinv(const float* __restrict__ A,
                                                     float* __restrict__ dinv,
                                                     float* __restrict__ rowsumP) {
    int row = blockIdx.x, tid = threadIdx.x;
    const float4* a4 = (const float4*)(A + (size_t)row * N);
    float s = 0.f;
    for (int j = tid; j < N / 4; j += 256) {
        float4 v = a4[j];
        s += v.x + v.y + v.z + v.w;
    }
    float tot = block_reduce_sum(s);
    if (tid == 0) {
        dinv[row] = rsqrtf(tot);
        rowsumP[row] = 0.f;  // init for k_gemm's atomics (ws is poisoned pre-launch)
    }
}

// ---------- K2: dmax = max(dinv), single block ----------
__global__ __launch_bounds__(1024) void k_dmax(const float* __restrict__ dinv,
                                               float* __restrict__ dmaxf) {
    int t = threadIdx.x;
    float m = fmaxf(fmaxf(dinv[t], dinv[t + 1024]), fmaxf(dinv[t + 2048], dinv[t + 3072]));
    #pragma unroll
    for (int off = 32; off; off >>= 1) m = fmaxf(m, __shfl_down(m, off));
    __shared__ float red[16];
    if ((t & 63) == 0) red[t >> 6] = m;
    __syncthreads();
    if (t == 0) {
        float mm = red[0];
        #pragma unroll
        for (int i = 1; i < 16; i++) mm = fmaxf(mm, red[i]);
        *dmaxf = mm;
    }
}

// ---------- K3: Sq = i8(S), Tq = i8(S^T); q = rint(S * 127/dmax^2) ----------
__global__ __launch_bounds__(256) void k_make_sqt(const float* __restrict__ A,
                                                  const float* __restrict__ dinv,
                                                  const float* __restrict__ dmaxf,
                                                  i8_t* __restrict__ Sq,
                                                  i8_t* __restrict__ Tq) {
    __shared__ float tile[64][65];
    int tid = threadIdx.x;
    int c4 = tid & 15;   // column group (4 cols)
    int rg = tid >> 4;   // 0..15
    int i0 = blockIdx.y * 64;
    int j0 = blockIdx.x * 64;
    float dmax = *dmaxf;
    float sinv = 127.0f / (dmax * dmax);
    float4 dj = *(const float4*)(dinv + j0 + 4 * c4);
    #pragma unroll
    for (int rr = 0; rr < 4; rr++) {
        int r = rg + 16 * rr;
        int row = i0 + r;
        float di = dinv[row];
        float4 av = *(const float4*)(A + (size_t)row * N + j0 + 4 * c4);
        float s0 = av.x * di * dj.x, s1 = av.y * di * dj.y;
        float s2 = av.z * di * dj.z, s3 = av.w * di * dj.w;
        i8x4 qv;
        qv[0] = (i8_t)(int)fminf(rintf(s0 * sinv), 127.f);
        qv[1] = (i8_t)(int)fminf(rintf(s1 * sinv), 127.f);
        qv[2] = (i8_t)(int)fminf(rintf(s2 * sinv), 127.f);
        qv[3] = (i8_t)(int)fminf(rintf(s3 * sinv), 127.f);
        *(i8x4*)(Sq + (size_t)row * N + j0 + 4 * c4) = qv;
        tile[r][4 * c4 + 0] = s0;
        tile[r][4 * c4 + 1] = s1;
        tile[r][4 * c4 + 2] = s2;
        tile[r][4 * c4 + 3] = s3;
    }
    __syncthreads();
    #pragma unroll
    for (int cc = 0; cc < 4; cc++) {
        int c = rg + 16 * cc;
        int gj = j0 + c;
        i8x4 qv;
        #pragma unroll
        for (int u = 0; u < 4; u++)
            qv[u] = (i8_t)(int)fminf(rintf(tile[4 * c4 + u][c] * sinv), 127.f);
        *(i8x4*)(Tq + (size_t)gj * N + i0 + 4 * c4) = qv;
    }
}

// ---------- K4: int8 GEMM + fused epilogue:
//   p = t1*s^2*(QQ^T) + t0*s*Q + I  (never materialized to HBM)
//   rowsumP += per-row sums (atomics); per-(row,block) top-4 candidates -> candV/candJ
//
// R5 restructure: T3-minimum 2-phase pipeline (catalog §5.5):
//   - staging double-buffered (2 x 16KB), ALIASED onto pbuf (staging dead after
//     K-loop, pbuf only used in epilogue) -> LDS 49.7KB -> 33.3KB -> 4 blocks/CU,
//     all 1024 blocks co-resident (removes the 3+1 tail round).
//   - counted s_waitcnt vmcnt(4): the 4 newest global_load_lds stay in flight
//     across both barriers + ds_reads + 16 MFMAs of the iteration (never drain
//     to 0 in steady state -- the old __syncthreads drained vmcnt(0) 2x/K-step,
//     zero stage/compute overlap within a wave).
//   - raw s_barrier; explicit lgkmcnt(0) before the 2nd barrier closes the
//     read-buf[p] vs next-iter stage-into-buf[p] hazard (m152 lesson).
//   - s_setprio(1) around the MFMA cluster (T5: phase-split now exists).
__global__ __launch_bounds__(256) void k_gemm(const i8_t* __restrict__ Sq,
                                              const i8_t* __restrict__ Tq,
                                              const float* __restrict__ dmaxf,
                                              const float* __restrict__ theta,
                                              float* __restrict__ rowsumP,
                                              float* __restrict__ candV,
                                              int* __restrict__ candJ) {
    // union: [buf p: As 8KB | Bs 8KB] x 2 (32KB) aliases pbuf (33.3KB)
    __shared__ __attribute__((aligned(64))) float pbuf[128][65];
    i8_t* const smem = (i8_t*)pbuf;

    int tid = threadIdx.x;
    int lane = tid & 63;
    int wave = tid >> 6;
    int wr = wave >> 1, wc = wave & 1;
    int bi = blockIdx.x, bj = blockIdx.y;

    // staging: thread t -> slot (row = t>>2 [+64], qslot = t&3); 16B chunks
    // XOR-swizzled global source chunk so LDS stays linear (lane x 16B).
    int qoff = ((tid & 3) ^ ((tid >> 3) & 3)) * 16;
    int row0 = tid >> 2;
    const i8_t* Ag0 = Sq + (size_t)(bi * 128 + row0) * N + qoff;
    const i8_t* Ag1 = Sq + (size_t)(bi * 128 + 64 + row0) * N + qoff;
    const i8_t* Bg0 = Tq + (size_t)(bj * 128 + row0) * N + qoff;
    const i8_t* Bg1 = Tq + (size_t)(bj * 128 + 64 + row0) * N + qoff;
    int l0 = tid * 16;            // rows 0..63 of the As/Bs region
    int l1 = (tid + 256) * 16;    // rows 64..127

    i32x4 acc[4][4];
    i32x4 z = {0, 0, 0, 0};
    #pragma unroll
    for (int i = 0; i < 4; i++)
        #pragma unroll
        for (int j = 0; j < 4; j++) acc[i][j] = z;

    int r = lane & 15, q = lane >> 4;
    int qs = q ^ ((r >> 1) & 3);  // fragment-read swizzle (2-way = free)
    int aoff = (wr * 64 + r) * 64 + qs * 16;
    int boff = (wc * 64 + r) * 64 + qs * 16;

    // prologue: stage K-tile 0 into buffer 0
    gload16(Ag0, smem + l0);
    gload16(Ag1, smem + l1);
    gload16(Bg0, smem + 8192 + l0);
    gload16(Bg1, smem + 8192 + l1);

    int p = 0;
    for (int t = 0; t < N / 64; ++t) {
        int k1 = (t + 1) * 64;
        if (k1 < N) {
            // issue next-tile stage into the other buffer; overlaps this whole iter
            i8_t* d = smem + (p ^ 1) * 16384;
            gload16(Ag0 + k1, d + l0);
            gload16(Ag1 + k1, d + l1);
            gload16(Bg0 + k1, d + 8192 + l0);
            gload16(Bg1 + k1, d + 8192 + l1);
            // counted wait: tile t's 4 loads (oldest) done, tile t+1's 4 stay in flight
            asm volatile("s_waitcnt vmcnt(4)" ::: "memory");
        } else {
            asm volatile("s_waitcnt vmcnt(0)" ::: "memory");
        }
        __builtin_amdgcn_s_barrier();  // all waves' tile-t staging visible

        const i8_t* Ab = smem + p * 16384;
        const i8_t* Bb = Ab + 8192;
        i32x4 af[4], bfr[4];
        #pragma unroll
        for (int mi = 0; mi < 4; mi++) af[mi] = *(const i32x4*)(Ab + aoff + mi * 16 * 64);
        #pragma unroll
        for (int ni = 0; ni < 4; ni++) bfr[ni] = *(const i32x4*)(Bb + boff + ni * 16 * 64);

        __builtin_amdgcn_s_setprio(1);
        #pragma unroll
        for (int mi = 0; mi < 4; mi++)
            #pragma unroll
            for (int ni = 0; ni < 4; ni++)
                acc[mi][ni] = __builtin_amdgcn_mfma_i32_16x16x64_i8(af[mi], bfr[ni],
                                                                    acc[mi][ni], 0, 0, 0);
        __builtin_amdgcn_s_setprio(0);

        // all our ds_reads of buf[p] complete before anyone may overwrite it next iter
        asm volatile("s_waitcnt lgkmcnt(0)" ::: "memory");
        __builtin_amdgcn_s_barrier();
        p ^= 1;
    }
    // after final barrier: vmcnt(0) drained at t=63, every wave's lgkmcnt(0) done
    // -> staging region dead, safe to reuse as pbuf.

    // ---- epilogue: p in place of acc (bit_cast reuse, no VGPR spike) ----
    float dmax = *dmaxf;
    float sq = dmax * dmax / 127.0f;
    float t0 = 1.f / (1.f + expf(-theta[0]));
    float t1 = 1.f / (1.f + expf(-theta[1]));
    float t0s = t0 * sq;
    float t1s2 = t1 * sq * sq;
    int col = lane & 15, quad = lane >> 4;

    #pragma unroll
    for (int mi = 0; mi < 4; mi++) {
        int gi0 = bi * 128 + wr * 64 + mi * 16 + quad * 4;
        float rsum[4] = {0.f, 0.f, 0.f, 0.f};
        #pragma unroll
        for (int ni = 0; ni < 4; ni++) {
            int gj = bj * 128 + wc * 64 + ni * 16 + col;
            f32x4 pf;
            #pragma unroll
            for (int rr = 0; rr < 4; rr++) {
                int gi = gi0 + rr;
                float qv = (float)Sq[(size_t)gi * N + gj];  // t0 term from quantized S
                float p2 = t1s2 * (float)acc[mi][ni][rr] + t0s * qv + ((gi == gj) ? 1.f : 0.f);
                pf[rr] = p2;
                rsum[rr] += p2;
            }
            acc[mi][ni] = __builtin_bit_cast(i32x4, pf);  // store p back into acc regs
        }
        #pragma unroll
        for (int rr = 0; rr < 4; rr++) {
            float v = rsum[rr];
            v += __shfl_xor(v, 1);
            v += __shfl_xor(v, 2);
            v += __shfl_xor(v, 4);
            v += __shfl_xor(v, 8);
            if (col == 0) atomicAdd(&rowsumP[gi0 + rr], v);
        }
    }

    // ---- two-pass LDS round-trip + per-row top-4 scan ----
    float bv[4] = {-FLT_MAX, -FLT_MAX, -FLT_MAX, -FLT_MAX};
    int bjx[4] = {N, N, N, N};
    int srow = tid >> 1;        // scan row 0..127
    int shalf = tid & 1;        // which 32-col half this thread scans

    #pragma unroll
    for (int pass = 0; pass < 2; pass++) {
        if (wc == pass) {
            #pragma unroll
            for (int mi = 0; mi < 4; mi++) {
                int prow = wr * 64 + mi * 16 + quad * 4;
                #pragma unroll
                for (int ni = 0; ni < 4; ni++) {
                    f32x4 pf = __builtin_bit_cast(f32x4, acc[mi][ni]);
                    #pragma unroll
                    for (int rr = 0; rr < 4; rr++)
                        pbuf[prow + rr][ni * 16 + col] = pf[rr];
                }
            }
        }
        __syncthreads();
        int jbase = bj * 128 + pass * 64 + shalf * 32;
        for (int i = 0; i < 32; i++)
            ins4(pbuf[srow][shalf * 32 + i], jbase + i, bv, bjx);
        __syncthreads();
    }

    // merge partner (t^1 scanned the other 32-col halves), write 4 candidates/row
    float ov[4]; int oj[4];
    #pragma unroll
    for (int c = 0; c < 4; c++) { ov[c] = __shfl_xor(bv[c], 1); oj[c] = __shfl_xor(bjx[c], 1); }
    #pragma unroll
    for (int c = 0; c < 4; c++) ins4(ov[c], oj[c], bv, bjx);
    if (shalf == 0) {
        size_t base = ((size_t)(bi * 128 + srow) * 32 + bj) * 4;
        #pragma unroll
        for (int c = 0; c < 4; c++) { candV[base + c] = bv[c]; candJ[base + c] = bjx[c]; }
    }
}

// ---------- K5: dinv2 = rsqrt(rowsumP) ----------
__global__ __launch_bounds__(256) void k_dinv2(const float* __restrict__ rowsumP,
                                               float* __restrict__ dinv2) {
    int g = blockIdx.x * 256 + threadIdx.x;
    dinv2[g] = rsqrtf(rowsumP[g]);
}

// ---------- K6: per-row final top-4 (exact dinv2 scaling) + fused output ----------
// 128 candidates/row; 64 threads x 2 candidates each (NOT 4 -- that over-ran the
// row segment and fabricated indices from float bit patterns -> OOB fault in R4).
__global__ __launch_bounds__(64) void k_final(const float* __restrict__ candV,
                                              const int* __restrict__ candJ,
                                              const float* __restrict__ dinv2,
                                              const float* __restrict__ x,
                                              const float* __restrict__ W,
                                              const float* __restrict__ bvec,
                                              const int* __restrict__ kin,
                                              float* __restrict__ out) {
    int row = blockIdx.x, t = threadIdx.x;
    float2 cv = *(const float2*)(candV + (size_t)row * 128 + t * 2);
    int2 cj = *(const int2*)(candJ + (size_t)row * 128 + t * 2);
    float bv[4] = {-FLT_MAX, -FLT_MAX, -FLT_MAX, -FLT_MAX};
    int bj[4] = {N, N, N, N};
    ins4(cv.x * dinv2[cj.x], cj.x, bv, bj);
    ins4(cv.y * dinv2[cj.y], cj.y, bv, bj);
    // butterfly merge across 64 lanes (disjoint sets at every step)
    #pragma unroll
    for (int off = 1; off < 64; off <<= 1) {
        float ov[4]; int oj[4];
        #pragma unroll
        for (int c = 0; c < 4; c++) { ov[c] = __shfl_xor(bv[c], off); oj[c] = __shfl_xor(bj[c], off); }
        #pragma unroll
        for (int c = 0; c < 4; c++) ins4(ov[c], oj[c], bv, bj);
    }
    // all lanes now hold the row's global top-4 (value = P_ij*dinv2_j, idx = j)
    int kk = kin[0];
    if (kk > 4) kk = 4;
    if (kk < 0) kk = 0;
    float sc = dinv2[row];
    float y = 0.f;
    for (int c = 0; c < kk; c++)
        y += sc * bv[c] * x[(size_t)bj[c] * DIN + t];
    __shared__ float ys[DIN];
    ys[t] = y;
    __syncthreads();
    const float4* w4 = (const float4*)(W + (size_t)t * DIN);
    const float4* y4 = (const float4*)ys;
    float o = bvec[t];
    #pragma unroll
    for (int d = 0; d < DIN / 4; d++) {
        float4 wv = w4[d], yv = y4[d];
        o += wv.x * yv.x + wv.y * yv.y + wv.z * yv.z + wv.w * yv.w;
    }
    out[(size_t)row * DIN + t] = o;
}

extern "C" void kernel_launch(void* const* d_in, const int* in_sizes, int n_in,
                              void* d_out, int out_size, void* d_ws, size_t ws_size,
                              hipStream_t stream) {
    const float* x = (const float*)d_in[0];
    const float* A = (const float*)d_in[1];
    const float* theta = (const float*)d_in[2];
    const float* W = (const float*)d_in[3];
    const float* b = (const float*)d_in[4];
    const int* kin = (const int*)d_in[5];
    float* out = (float*)d_out;

    // workspace layout (~38 MB)
    char* ws = (char*)d_ws;
    i8_t* Sq = (i8_t*)ws;                                  // 16 MB
    i8_t* Tq = (i8_t*)(ws + (size_t)N * N);                // 16 MB
    float* candV = (float*)(ws + (size_t)N * N * 2);       // 2 MB
    int* candJ = (int*)(ws + (size_t)N * N * 2 + (size_t)N * 128 * 4);  // 2 MB
    float* dinv = (float*)(ws + (size_t)N * N * 2 + (size_t)N * 128 * 8);
    float* dinv2 = dinv + N;
    float* rowsumP = dinv2 + N;
    float* dmaxf = rowsumP + N;

    k_rowsum_dinv<<<N, 256, 0, stream>>>(A, dinv, rowsumP);
    k_dmax<<<1, 1024, 0, stream>>>(dinv, dmaxf);
    k_make_sqt<<<dim3(64, 64), 256, 0, stream>>>(A, dinv, dmaxf, Sq, Tq);
    k_gemm<<<dim3(32, 32), 256, 0, stream>>>(Sq, Tq, dmaxf, theta, rowsumP, candV, candJ);
    k_dinv2<<<N / 256, 256, 0, stream>>>(rowsumP, dinv2);
    k_final<<<N, 64, 0, stream>>>(candV, candJ, dinv2, x, W, b, kin, out);
}

// Round 2
// 252.313 us; speedup vs baseline: 1.0989x; 1.0592x over previous
//
#include <hip/hip_runtime.h>
#include <hip/hip_bf16.h>
#include <float.h>
#include <math.h>

#define N 4096
#define DIN 64

typedef signed char i8_t;
typedef signed char i8x4 __attribute__((ext_vector_type(4)));
typedef int i32x4 __attribute__((ext_vector_type(4)));
typedef float f32x4 __attribute__((ext_vector_type(4)));

// ---------- async global->LDS, 16B per lane ----------
__device__ __forceinline__ void gload16(const void* g, void* l) {
    __builtin_amdgcn_global_load_lds((const __attribute__((address_space(1))) void*)g,
                                     (__attribute__((address_space(3))) void*)l,
                                     16, 0, 0);
}

__device__ __forceinline__ float block_reduce_sum(float s) {
    __shared__ float red[4];
    #pragma unroll
    for (int off = 32; off; off >>= 1) s += __shfl_down(s, off);
    if ((threadIdx.x & 63) == 0) red[threadIdx.x >> 6] = s;
    __syncthreads();
    return red[0] + red[1] + red[2] + red[3];
}

// ---------- top-4 insertion with tie -> lower index ----------
__device__ __forceinline__ bool better(float v1, int j1, float v2, int j2) {
    return v1 > v2 || (v1 == v2 && j1 < j2);
}
__device__ __forceinline__ void ins4(float v, int j, float bv[4], int bj[4]) {
    if (!better(v, j, bv[3], bj[3])) return;
    bv[3] = v; bj[3] = j;
    if (better(bv[3], bj[3], bv[2], bj[2])) {
        float tv = bv[2]; int tj = bj[2]; bv[2] = bv[3]; bj[2] = bj[3]; bv[3] = tv; bj[3] = tj;
    }
    if (better(bv[2], bj[2], bv[1], bj[1])) {
        float tv = bv[1]; int tj = bj[1]; bv[1] = bv[2]; bj[1] = bj[2]; bv[2] = tv; bj[2] = tj;
    }
    if (better(bv[1], bj[1], bv[0], bj[0])) {
        float tv = bv[0]; int tj = bj[0]; bv[0] = bv[1]; bj[0] = bj[1]; bv[1] = tv; bj[1] = tj;
    }
}

// ---------- K1: rowsums of A -> dinv = 1/sqrt(d); also zero rowsumP ----------
__global__ __launch_bounds__(256) void k_rowsum_dinv(const float* __restrict__ A,
                                                     float* __restrict__ dinv,
                                                     float* __restrict__ rowsumP) {
    int row = blockIdx.x, tid = threadIdx.x;
    const float4* a4 = (const float4*)(A + (size_t)row * N);
    float s = 0.f;
    for (int j = tid; j < N / 4; j += 256) {
        float4 v = a4[j];
        s += v.x + v.y + v.z + v.w;
    }
    float tot = block_reduce_sum(s);
    if (tid == 0) {
        dinv[row] = rsqrtf(tot);
        rowsumP[row] = 0.f;  // init for k_gemm's atomics (ws is poisoned pre-launch)
    }
}

// ---------- K2: dmax = max(dinv), single block ----------
__global__ __launch_bounds__(1024) void k_dmax(const float* __restrict__ dinv,
                                               float* __restrict__ dmaxf) {
    int t = threadIdx.x;
    float m = fmaxf(fmaxf(dinv[t], dinv[t + 1024]), fmaxf(dinv[t + 2048], dinv[t + 3072]));
    #pragma unroll
    for (int off = 32; off; off >>= 1) m = fmaxf(m, __shfl_down(m, off));
    __shared__ float red[16];
    if ((t & 63) == 0) red[t >> 6] = m;
    __syncthreads();
    if (t == 0) {
        float mm = red[0];
        #pragma unroll
        for (int i = 1; i < 16; i++) mm = fmaxf(mm, red[i]);
        *dmaxf = mm;
    }
}

// ---------- K3: Sq = i8(S), Tq = i8(S^T); q = rint(S * 127/dmax^2) ----------
__global__ __launch_bounds__(256) void k_make_sqt(const float* __restrict__ A,
                                                  const float* __restrict__ dinv,
                                                  const float* __restrict__ dmaxf,
                                                  i8_t* __restrict__ Sq,
                                                  i8_t* __restrict__ Tq) {
    __shared__ float tile[64][65];
    int tid = threadIdx.x;
    int c4 = tid & 15;   // column group (4 cols)
    int rg = tid >> 4;   // 0..15
    int i0 = blockIdx.y * 64;
    int j0 = blockIdx.x * 64;
    float dmax = *dmaxf;
    float sinv = 127.0f / (dmax * dmax);
    float4 dj = *(const float4*)(dinv + j0 + 4 * c4);
    #pragma unroll
    for (int rr = 0; rr < 4; rr++) {
        int r = rg + 16 * rr;
        int row = i0 + r;
        float di = dinv[row];
        float4 av = *(const float4*)(A + (size_t)row * N + j0 + 4 * c4);
        float s0 = av.x * di * dj.x, s1 = av.y * di * dj.y;
        float s2 = av.z * di * dj.z, s3 = av.w * di * dj.w;
        i8x4 qv;
        qv[0] = (i8_t)(int)fminf(rintf(s0 * sinv), 127.f);
        qv[1] = (i8_t)(int)fminf(rintf(s1 * sinv), 127.f);
        qv[2] = (i8_t)(int)fminf(rintf(s2 * sinv), 127.f);
        qv[3] = (i8_t)(int)fminf(rintf(s3 * sinv), 127.f);
        *(i8x4*)(Sq + (size_t)row * N + j0 + 4 * c4) = qv;
        tile[r][4 * c4 + 0] = s0;
        tile[r][4 * c4 + 1] = s1;
        tile[r][4 * c4 + 2] = s2;
        tile[r][4 * c4 + 3] = s3;
    }
    __syncthreads();
    #pragma unroll
    for (int cc = 0; cc < 4; cc++) {
        int c = rg + 16 * cc;
        int gj = j0 + c;
        i8x4 qv;
        #pragma unroll
        for (int u = 0; u < 4; u++)
            qv[u] = (i8_t)(int)fminf(rintf(tile[4 * c4 + u][c] * sinv), 127.f);
        *(i8x4*)(Tq + (size_t)gj * N + i0 + 4 * c4) = qv;
    }
}

// ---------- K3b: XW = x @ W^T  (4096x64 @ 64x64) ----------
// Precomputing this turns k_final's per-block 64x64 W-dot (every block re-read
// all of W) into a 4-row gather+FMA. Reassociation (S@(xW^T) vs (S@x)W^T) is
// well inside the int8-quantization error we already pass with.
__global__ __launch_bounds__(256) void k_xw(const float* __restrict__ x,
                                            const float* __restrict__ W,
                                            float* __restrict__ XW) {
    __shared__ float Wl[64][65];   // padded: bank (o+d)%32, conflict-free
    __shared__ float xs[4][64];
    int tid = threadIdx.x;
    for (int i = tid; i < 64 * 64; i += 256) Wl[i >> 6][i & 63] = W[i];
    int r = tid >> 6, o = tid & 63;
    int row = blockIdx.x * 4 + r;
    xs[r][o] = x[(size_t)row * DIN + o];
    __syncthreads();
    float acc = 0.f;
    #pragma unroll
    for (int d = 0; d < 64; d++) acc += xs[r][d] * Wl[o][d];
    XW[(size_t)row * DIN + o] = acc;
}

// ---------- K4: int8 GEMM + fused epilogue:
//   p = t1*s^2*(QQ^T) + t0*s*Q + I  (never materialized to HBM)
//   rowsumP += per-row sums (atomics); per-(row,block) top-4 candidates -> candV/candJ
//
// R6: XCD-chunked 2D block swizzle (T1). Aggregate panel re-reads are ~1.05 GB
// per dispatch (9.1 TB/s at R5's 115 us) served by L3 since panels are scattered
// across XCDs -> L3-BW-bound. Rectangular chunking (each XCD = 16(bi) x 8(bj)
// rect) gives each XCD 16 Sq-panels + 8 Tq-panels = 12 MB unique (L3 once),
// with all re-reads hitting the XCD-private L2 (2.6 TB/s/XCD < 4.3 capacity).
// R5 pipeline (2-phase dbuf, counted vmcnt(4), raw barriers, setprio) kept.
__global__ __launch_bounds__(256) void k_gemm(const i8_t* __restrict__ Sq,
                                              const i8_t* __restrict__ Tq,
                                              const float* __restrict__ dmaxf,
                                              const float* __restrict__ theta,
                                              float* __restrict__ rowsumP,
                                              float* __restrict__ candV,
                                              int* __restrict__ candJ) {
    // union: [buf p: As 8KB | Bs 8KB] x 2 (32KB) aliases pbuf (33.3KB)
    __shared__ __attribute__((aligned(64))) float pbuf[128][65];
    i8_t* const smem = (i8_t*)pbuf;

    int tid = threadIdx.x;
    int lane = tid & 63;
    int wave = tid >> 6;
    int wr = wave >> 1, wc = wave & 1;

    // XCD-chunked swizzle: xcd = bid&7 (hw round-robin), 128 blocks/XCD as a
    // 16x8 (bi x bj) rectangle. Bijective on the 32x32 grid.
    int bid = blockIdx.x;
    int xcd = bid & 7, local = bid >> 3;
    int bi = ((xcd & 1) << 4) + (local & 15);
    int bj = ((xcd >> 1) << 3) + (local >> 4);

    // staging: thread t -> slot (row = t>>2 [+64], qslot = t&3); 16B chunks
    // XOR-swizzled global source chunk so LDS stays linear (lane x 16B).
    int qoff = ((tid & 3) ^ ((tid >> 3) & 3)) * 16;
    int row0 = tid >> 2;
    const i8_t* Ag0 = Sq + (size_t)(bi * 128 + row0) * N + qoff;
    const i8_t* Ag1 = Sq + (size_t)(bi * 128 + 64 + row0) * N + qoff;
    const i8_t* Bg0 = Tq + (size_t)(bj * 128 + row0) * N + qoff;
    const i8_t* Bg1 = Tq + (size_t)(bj * 128 + 64 + row0) * N + qoff;
    int l0 = tid * 16;            // rows 0..63 of the As/Bs region
    int l1 = (tid + 256) * 16;    // rows 64..127

    i32x4 acc[4][4];
    i32x4 z = {0, 0, 0, 0};
    #pragma unroll
    for (int i = 0; i < 4; i++)
        #pragma unroll
        for (int j = 0; j < 4; j++) acc[i][j] = z;

    int r = lane & 15, q = lane >> 4;
    int qs = q ^ ((r >> 1) & 3);  // fragment-read swizzle (2-way = free)
    int aoff = (wr * 64 + r) * 64 + qs * 16;
    int boff = (wc * 64 + r) * 64 + qs * 16;

    // prologue: stage K-tile 0 into buffer 0
    gload16(Ag0, smem + l0);
    gload16(Ag1, smem + l1);
    gload16(Bg0, smem + 8192 + l0);
    gload16(Bg1, smem + 8192 + l1);

    int p = 0;
    for (int t = 0; t < N / 64; ++t) {
        int k1 = (t + 1) * 64;
        if (k1 < N) {
            // issue next-tile stage into the other buffer; overlaps this whole iter
            i8_t* d = smem + (p ^ 1) * 16384;
            gload16(Ag0 + k1, d + l0);
            gload16(Ag1 + k1, d + l1);
            gload16(Bg0 + k1, d + 8192 + l0);
            gload16(Bg1 + k1, d + 8192 + l1);
            // counted wait: tile t's 4 loads (oldest) done, tile t+1's 4 stay in flight
            asm volatile("s_waitcnt vmcnt(4)" ::: "memory");
        } else {
            asm volatile("s_waitcnt vmcnt(0)" ::: "memory");
        }
        __builtin_amdgcn_s_barrier();  // all waves' tile-t staging visible

        const i8_t* Ab = smem + p * 16384;
        const i8_t* Bb = Ab + 8192;
        i32x4 af[4], bfr[4];
        #pragma unroll
        for (int mi = 0; mi < 4; mi++) af[mi] = *(const i32x4*)(Ab + aoff + mi * 16 * 64);
        #pragma unroll
        for (int ni = 0; ni < 4; ni++) bfr[ni] = *(const i32x4*)(Bb + boff + ni * 16 * 64);

        __builtin_amdgcn_s_setprio(1);
        #pragma unroll
        for (int mi = 0; mi < 4; mi++)
            #pragma unroll
            for (int ni = 0; ni < 4; ni++)
                acc[mi][ni] = __builtin_amdgcn_mfma_i32_16x16x64_i8(af[mi], bfr[ni],
                                                                    acc[mi][ni], 0, 0, 0);
        __builtin_amdgcn_s_setprio(0);

        // all our ds_reads of buf[p] complete before anyone may overwrite it next iter
        asm volatile("s_waitcnt lgkmcnt(0)" ::: "memory");
        __builtin_amdgcn_s_barrier();
        p ^= 1;
    }
    // after final barrier: vmcnt(0) drained at t=63, every wave's lgkmcnt(0) done
    // -> staging region dead, safe to reuse as pbuf.

    // ---- epilogue: p in place of acc (bit_cast reuse, no VGPR spike) ----
    float dmax = *dmaxf;
    float sq = dmax * dmax / 127.0f;
    float t0 = 1.f / (1.f + expf(-theta[0]));
    float t1 = 1.f / (1.f + expf(-theta[1]));
    float t0s = t0 * sq;
    float t1s2 = t1 * sq * sq;
    int col = lane & 15, quad = lane >> 4;

    #pragma unroll
    for (int mi = 0; mi < 4; mi++) {
        int gi0 = bi * 128 + wr * 64 + mi * 16 + quad * 4;
        float rsum[4] = {0.f, 0.f, 0.f, 0.f};
        #pragma unroll
        for (int ni = 0; ni < 4; ni++) {
            int gj = bj * 128 + wc * 64 + ni * 16 + col;
            f32x4 pf;
            #pragma unroll
            for (int rr = 0; rr < 4; rr++) {
                int gi = gi0 + rr;
                float qv = (float)Sq[(size_t)gi * N + gj];  // t0 term from quantized S
                float p2 = t1s2 * (float)acc[mi][ni][rr] + t0s * qv + ((gi == gj) ? 1.f : 0.f);
                pf[rr] = p2;
                rsum[rr] += p2;
            }
            acc[mi][ni] = __builtin_bit_cast(i32x4, pf);  // store p back into acc regs
        }
        #pragma unroll
        for (int rr = 0; rr < 4; rr++) {
            float v = rsum[rr];
            v += __shfl_xor(v, 1);
            v += __shfl_xor(v, 2);
            v += __shfl_xor(v, 4);
            v += __shfl_xor(v, 8);
            if (col == 0) atomicAdd(&rowsumP[gi0 + rr], v);
        }
    }

    // ---- two-pass LDS round-trip + per-row top-4 scan ----
    float bv[4] = {-FLT_MAX, -FLT_MAX, -FLT_MAX, -FLT_MAX};
    int bjx[4] = {N, N, N, N};
    int srow = tid >> 1;        // scan row 0..127
    int shalf = tid & 1;        // which 32-col half this thread scans

    #pragma unroll
    for (int pass = 0; pass < 2; pass++) {
        if (wc == pass) {
            #pragma unroll
            for (int mi = 0; mi < 4; mi++) {
                int prow = wr * 64 + mi * 16 + quad * 4;
                #pragma unroll
                for (int ni = 0; ni < 4; ni++) {
                    f32x4 pf = __builtin_bit_cast(f32x4, acc[mi][ni]);
                    #pragma unroll
                    for (int rr = 0; rr < 4; rr++)
                        pbuf[prow + rr][ni * 16 + col] = pf[rr];
                }
            }
        }
        __syncthreads();
        int jbase = bj * 128 + pass * 64 + shalf * 32;
        for (int i = 0; i < 32; i++)
            ins4(pbuf[srow][shalf * 32 + i], jbase + i, bv, bjx);
        __syncthreads();
    }

    // merge partner (t^1 scanned the other 32-col halves), write 4 candidates/row
    float ov[4]; int oj[4];
    #pragma unroll
    for (int c = 0; c < 4; c++) { ov[c] = __shfl_xor(bv[c], 1); oj[c] = __shfl_xor(bjx[c], 1); }
    #pragma unroll
    for (int c = 0; c < 4; c++) ins4(ov[c], oj[c], bv, bjx);
    if (shalf == 0) {
        size_t base = ((size_t)(bi * 128 + srow) * 32 + bj) * 4;
        #pragma unroll
        for (int c = 0; c < 4; c++) { candV[base + c] = bv[c]; candJ[base + c] = bjx[c]; }
    }
}

// ---------- K5: dinv2 = rsqrt(rowsumP) ----------
__global__ __launch_bounds__(256) void k_dinv2(const float* __restrict__ rowsumP,
                                               float* __restrict__ dinv2) {
    int g = blockIdx.x * 256 + threadIdx.x;
    dinv2[g] = rsqrtf(rowsumP[g]);
}

// ---------- K6: per-row final top-4 (exact dinv2 scaling) + gather of XW ----------
// 128 candidates/row; 64 threads x 2 candidates each (NOT 4 -- that over-ran the
// row segment and fabricated indices from float bit patterns -> OOB fault in R4).
// R6: W-dot moved out (k_xw); here just out = b + sum_c sc*bv_c*XW[j_c].
__global__ __launch_bounds__(64) void k_final(const float* __restrict__ candV,
                                              const int* __restrict__ candJ,
                                              const float* __restrict__ dinv2,
                                              const float* __restrict__ XW,
                                              const float* __restrict__ bvec,
                                              const int* __restrict__ kin,
                                              float* __restrict__ out) {
    int row = blockIdx.x, t = threadIdx.x;
    float2 cv = *(const float2*)(candV + (size_t)row * 128 + t * 2);
    int2 cj = *(const int2*)(candJ + (size_t)row * 128 + t * 2);
    float bv[4] = {-FLT_MAX, -FLT_MAX, -FLT_MAX, -FLT_MAX};
    int bj[4] = {N, N, N, N};
    ins4(cv.x * dinv2[cj.x], cj.x, bv, bj);
    ins4(cv.y * dinv2[cj.y], cj.y, bv, bj);
    // butterfly merge across 64 lanes (disjoint sets at every step)
    #pragma unroll
    for (int off = 1; off < 64; off <<= 1) {
        float ov[4]; int oj[4];
        #pragma unroll
        for (int c = 0; c < 4; c++) { ov[c] = __shfl_xor(bv[c], off); oj[c] = __shfl_xor(bj[c], off); }
        #pragma unroll
        for (int c = 0; c < 4; c++) ins4(ov[c], oj[c], bv, bj);
    }
    // all lanes now hold the row's global top-4 (value = P_ij*dinv2_j, idx = j)
    int kk = kin[0];
    if (kk > 4) kk = 4;
    if (kk < 0) kk = 0;
    float sc = dinv2[row];
    float o = bvec[t];
    for (int c = 0; c < kk; c++)
        o += sc * bv[c] * XW[(size_t)bj[c] * DIN + t];
    out[(size_t)row * DIN + t] = o;
}

extern "C" void kernel_launch(void* const* d_in, const int* in_sizes, int n_in,
                              void* d_out, int out_size, void* d_ws, size_t ws_size,
                              hipStream_t stream) {
    const float* x = (const float*)d_in[0];
    const float* A = (const float*)d_in[1];
    const float* theta = (const float*)d_in[2];
    const float* W = (const float*)d_in[3];
    const float* b = (const float*)d_in[4];
    const int* kin = (const int*)d_in[5];
    float* out = (float*)d_out;

    // workspace layout (~37.2 MB)
    char* ws = (char*)d_ws;
    i8_t* Sq = (i8_t*)ws;                                  // 16 MB
    i8_t* Tq = (i8_t*)(ws + (size_t)N * N);                // 16 MB
    float* candV = (float*)(ws + (size_t)N * N * 2);       // 2 MB
    int* candJ = (int*)(ws + (size_t)N * N * 2 + (size_t)N * 128 * 4);  // 2 MB
    float* dinv = (float*)(ws + (size_t)N * N * 2 + (size_t)N * 128 * 8);
    float* dinv2 = dinv + N;
    float* rowsumP = dinv2 + N;
    float* dmaxf = rowsumP + N;
    float* XW = (float*)(ws + (size_t)N * N * 2 + (size_t)N * 128 * 8 + 65536);  // 1 MB

    k_xw<<<N / 4, 256, 0, stream>>>(x, W, XW);
    k_rowsum_dinv<<<N, 256, 0, stream>>>(A, dinv, rowsumP);
    k_dmax<<<1, 1024, 0, stream>>>(dinv, dmaxf);
    k_make_sqt<<<dim3(64, 64), 256, 0, stream>>>(A, dinv, dmaxf, Sq, Tq);
    k_gemm<<<1024, 256, 0, stream>>>(Sq, Tq, dmaxf, theta, rowsumP, candV, candJ);
    k_dinv2<<<N / 256, 256, 0, stream>>>(rowsumP, dinv2);
    k_final<<<N, 64, 0, stream>>>(candV, candJ, dinv2, XW, b, kin, out);
}